// Round 13
// baseline (293.459 us; speedup 1.0000x reference)
//
#include <hip/hip_runtime.h>
#include <stdint.h>

typedef int v4i __attribute__((ext_vector_type(4)));

#define M_DIM 8192   // B*S = 2*4096
#define N_DIM 8192   // OUT
#define K_DIM 2048   // IN
#define RISKY_TAU 1e-4f
#define BUCKET_CAP 1024
#define SLOT 32768   // LDS slot: A[256][64] 16KB + B[256][64] 16KB

// async global->LDS, 16B per lane (dest = wave-uniform base + lane*16)
#define ASYNC16(g, l) __builtin_amdgcn_global_load_lds(                        \
    (const __attribute__((address_space(1))) void*)(uintptr_t)(g),             \
    (__attribute__((address_space(3))) void*)(uint32_t)(uintptr_t)(l), 16, 0, 0)

// ---------------- 1) numpy-pairwise f32 sum of |w| ----------------
__global__ __launch_bounds__(256) void abssum_stage1(const float* __restrict__ w,
                                                     float* __restrict__ s1) {
  int b = blockIdx.x * 256 + threadIdx.x;  // 131072 leaf blocks of 128
  const float* p = w + (size_t)b * 128;
  float r[8];
#pragma unroll
  for (int j = 0; j < 8; j++) r[j] = fabsf(p[j]);
  for (int i = 8; i < 128; i += 8) {
#pragma unroll
    for (int j = 0; j < 8; j++) r[j] += fabsf(p[i + j]);
  }
  s1[b] = ((r[0] + r[1]) + (r[2] + r[3])) + ((r[4] + r[5]) + (r[6] + r[7]));
}

__global__ __launch_bounds__(256) void abssum_stage2(const float* __restrict__ s1,
                                                     float* __restrict__ s2) {
  int t = blockIdx.x * 256 + threadIdx.x;  // 4096 threads
  float v[32];
#pragma unroll
  for (int i = 0; i < 32; i++) v[i] = s1[t * 32 + i];
#pragma unroll
  for (int s = 1; s < 32; s *= 2) {
#pragma unroll
    for (int i = 0; i < 32; i += 2 * s) v[i] += v[i + s];
  }
  s2[t] = v[0];
}

__global__ __launch_bounds__(256) void gamma_stage3(const float* __restrict__ s2,
                                                    float* __restrict__ gp) {
  int t = threadIdx.x;  // 256 threads, one block
  float v[16];
#pragma unroll
  for (int i = 0; i < 16; i++) v[i] = s2[t * 16 + i];
#pragma unroll
  for (int s = 1; s < 16; s *= 2) {
#pragma unroll
    for (int i = 0; i < 16; i += 2 * s) v[i] += v[i + s];
  }
  __shared__ float sm[256];
  sm[t] = v[0];
  for (int s = 1; s < 256; s *= 2) {
    __syncthreads();
    if ((t & (2 * s - 1)) == 0) sm[t] += sm[t + s];
  }
  __syncthreads();
  if (t == 0) {
    float g = sm[0] * 0x1p-24f;  // /(8192*2048), exact pow2 scale
    gp[0] = fmaxf(g, 1e-5f);
  }
}

__global__ void zero_counts(int* __restrict__ counts) {
  counts[threadIdx.x] = 0;
}

// ---------------- 2) ternary weight quant + risky-midpoint detection ----------------
__global__ __launch_bounds__(256) void wq_kernel(const float4* __restrict__ w4,
                                                 const float* __restrict__ gp,
                                                 int* __restrict__ wq,
                                                 int* __restrict__ counts,
                                                 int* __restrict__ buckets) {
  int i = blockIdx.x * 256 + threadIdx.x;
  float g = gp[0];
  float4 v = w4[i];
  float e[4] = {v.x, v.y, v.z, v.w};
  int q[4];
#pragma unroll
  for (int c = 0; c < 4; c++) {
    q[c] = (int)rintf(fminf(fmaxf(e[c] / g, -1.0f), 1.0f));
    float t = fabsf(e[c]) / g;
    if (fabsf(t - 0.5f) < RISKY_TAU) {
      int flat = i * 4 + c;
      int n = flat >> 11;          // weight row (output col)
      int k = flat & 2047;
      int sgn_neg = (e[c] < 0.0f) ? 1 : 0;
      int sbit = (q[c] == 0) ? sgn_neg : (1 - sgn_neg);
      int b = n >> 7;
      int idx = atomicAdd(&counts[b], 1);
      if (idx < BUCKET_CAP)
        buckets[b * BUCKET_CAP + idx] = k | (n << 11) | (sbit << 24);
    }
  }
  wq[i] = (q[0] & 0xFF) | ((q[1] & 0xFF) << 8) | ((q[2] & 0xFF) << 16) | ((q[3] & 0xFF) << 24);
}

// ---------------- 3) fused LayerNorm + absmax int8 quant (one block per row) ----------------
__global__ __launch_bounds__(256) void lnq_kernel(const float* __restrict__ x,
                                                  const float* __restrict__ gp,
                                                  int8_t* __restrict__ xq,
                                                  float* __restrict__ scales) {
  const int row = blockIdx.x;
  const int t = threadIdx.x;
  const float4* xr = (const float4*)(x + (size_t)row * K_DIM);
  float4 a = xr[t];
  float4 b = xr[t + 256];
  double v[8] = {a.x, a.y, a.z, a.w, b.x, b.y, b.z, b.w};
  double s = 0.0, ss = 0.0;
#pragma unroll
  for (int i = 0; i < 8; i++) { s += v[i]; ss += v[i] * v[i]; }
  __shared__ double sm1[256], sm2[256];
  sm1[t] = s; sm2[t] = ss;
  __syncthreads();
  for (int off = 128; off > 0; off >>= 1) {
    if (t < off) { sm1[t] += sm1[t + off]; sm2[t] += sm2[t + off]; }
    __syncthreads();
  }
  double mu = sm1[0] * (1.0 / 2048.0);
  double var = sm2[0] * (1.0 / 2048.0) - mu * mu;  // biased variance
  double inv = 1.0 / sqrt(var + 1e-5);
  __syncthreads();
  double mx = 0.0;
#pragma unroll
  for (int i = 0; i < 8; i++) {
    v[i] = (v[i] - mu) * inv;
    double av = fabs(v[i]);
    if (av > mx) mx = av;
  }
  sm1[t] = mx;
  __syncthreads();
  for (int off = 128; off > 0; off >>= 1) {
    if (t < off) sm1[t] = fmax(sm1[t], sm1[t + off]);
    __syncthreads();
  }
  double eta = fmax(sm1[0], 1e-5);
  double r = 127.0 / eta;
  int q[8];
#pragma unroll
  for (int i = 0; i < 8; i++) {
    double qq = rint(v[i] * r);  // round-half-even, then clip
    qq = fmin(fmax(qq, -128.0), 127.0);
    q[i] = (int)qq;
  }
  int p0 = (q[0] & 0xFF) | ((q[1] & 0xFF) << 8) | ((q[2] & 0xFF) << 16) | ((q[3] & 0xFF) << 24);
  int p1 = (q[4] & 0xFF) | ((q[5] & 0xFF) << 8) | ((q[6] & 0xFF) << 16) | ((q[7] & 0xFF) << 24);
  int* orow = (int*)(xq + (size_t)row * K_DIM);
  orow[t] = p0;
  orow[t + 256] = p1;
  if (t == 0) scales[row] = (float)((double)gp[0] * eta * (1.0 / 127.0));
}

// ---------------- 4) int8 MFMA GEMM: 256x256, 8 waves, ring-3, 4-phase interleave -------
// r12 skeleton (ring-3 slots, counted vmcnt(4), slab swizzle, (r>>1)&3 LDS swizzle) with
// the K-step split into 4 fine phases (8-phase-template analog for i8 K=64):
//   phase p: {ds_read subtile || issue 1 global_load_lds for tile t+2} -> s_barrier ->
//            setprio(1) -> 8 MFMA -> setprio(0) -> s_barrier
// vmcnt(4) folded into phase 3 (never 0 in-loop). Phases are scheduling-only: correctness
// still rests on the once-per-step vmcnt+barrier publish chain (proven in r12).
__global__ __launch_bounds__(512) void gemm_i8_kernel(const int8_t* __restrict__ A,
                                                      const int8_t* __restrict__ B,
                                                      const float* __restrict__ scales,
                                                      const float* __restrict__ bias,
                                                      const int* __restrict__ counts,
                                                      const int* __restrict__ buckets,
                                                      float* __restrict__ C) {
  __shared__ alignas(16) int8_t lds[3 * SLOT];  // 96 KiB
  const int tid = threadIdx.x;
  const int wave = tid >> 6;   // 0..7
  const int lane = tid & 63;

  // XCD slab swizzle: 1024 blocks, xcd = b&7 owns tile rows [4*xcd, 4*xcd+4), col-major
  const int b = blockIdx.x;
  const int tr = (b & 7) * 4 + ((b >> 3) & 3);
  const int tc = b >> 5;
  const int brow = tr * 256;
  const int bcol = tc * 256;

  // staging: per matrix 16 chunks of 1KB (16 rows x 64B); wave w stages chunks {2w,2w+1}.
  const int chunkr = lane >> 2;
  const int sl = lane & 3;
  const int8_t* gA[2];
  const int8_t* gB[2];
  int dA[2], dB[2];
#pragma unroll
  for (int c = 0; c < 2; c++) {
    int ch = wave * 2 + c;
    int r = ch * 16 + chunkr;
    int scol = ((sl ^ ((r >> 1) & 3)) << 4);
    gA[c] = A + (size_t)(brow + r) * K_DIM + scol;
    gB[c] = B + (size_t)(bcol + r) * K_DIM + scol;
    dA[c] = ch * 1024;           // wave-uniform LDS base (+lane*16 by HW)
    dB[c] = 16384 + ch * 1024;
  }

  // fragment read offsets (swizzled), slot-relative
  const int wr = wave >> 2;    // 0..1  (M half)
  const int wc = wave & 3;     // 0..3  (N quarter)
  const int ks = lane >> 4;    // k-slot 0..3
  int aoff[8], boff[4];
#pragma unroll
  for (int m = 0; m < 8; m++) {
    int r = wr * 128 + m * 16 + (lane & 15);
    aoff[m] = r * 64 + ((ks ^ ((r >> 1) & 3)) << 4);
  }
#pragma unroll
  for (int n = 0; n < 4; n++) {
    int r = wc * 64 + n * 16 + (lane & 15);
    boff[n] = 16384 + r * 64 + ((ks ^ ((r >> 1) & 3)) << 4);
  }

  v4i acc[8][4];
  const v4i vzero = {0, 0, 0, 0};
#pragma unroll
  for (int m = 0; m < 8; m++)
#pragma unroll
    for (int n = 0; n < 4; n++) acc[m][n] = vzero;

  // prologue: stage tile 0 -> slot 0, tile 1 -> slot 1 (4 loads/wave each)
#pragma unroll
  for (int c = 0; c < 2; c++) {
    ASYNC16(gA[c], lds + dA[c]);
    ASYNC16(gB[c], lds + dB[c]);
  }
#pragma unroll
  for (int c = 0; c < 2; c++) {
    ASYNC16(gA[c] + 64, lds + SLOT + dA[c]);
    ASYNC16(gB[c] + 64, lds + SLOT + dB[c]);
  }
  asm volatile("s_waitcnt vmcnt(4)" ::: "memory");  // tile 0 landed
  __builtin_amdgcn_s_barrier();

#define MFMA2(M)                                                               \
  _Pragma("unroll") for (int n = 0; n < 4; n++)                                \
    acc[M][n] = __builtin_amdgcn_mfma_i32_16x16x64_i8(af[M], bf[n], acc[M][n], 0, 0, 0); \
  _Pragma("unroll") for (int n = 0; n < 4; n++)                                \
    acc[M + 1][n] = __builtin_amdgcn_mfma_i32_16x16x64_i8(af[M + 1], bf[n], acc[M + 1][n], 0, 0, 0);

  int rbase = 0;         // read slot base
  int sbase = 2 * SLOT;  // stage slot base
  for (int t = 0; t < 32; ++t) {
    const int kt = (t + 2) * 64;
    const bool st = (t < 30);
    v4i bf[4], af[8];
    // ---- phase 0: B frags + A frags 0,1 ; stage A-chunk 0
    bf[0] = *(const v4i*)(lds + rbase + boff[0]);
    bf[1] = *(const v4i*)(lds + rbase + boff[1]);
    bf[2] = *(const v4i*)(lds + rbase + boff[2]);
    bf[3] = *(const v4i*)(lds + rbase + boff[3]);
    af[0] = *(const v4i*)(lds + rbase + aoff[0]);
    af[1] = *(const v4i*)(lds + rbase + aoff[1]);
    if (st) ASYNC16(gA[0] + kt, lds + sbase + dA[0]);
    __builtin_amdgcn_s_barrier();
    __builtin_amdgcn_s_setprio(1);
    MFMA2(0)
    __builtin_amdgcn_s_setprio(0);
    __builtin_amdgcn_s_barrier();
    asm volatile("" ::: "memory");
    // ---- phase 1: A frags 2,3 ; stage A-chunk 1
    af[2] = *(const v4i*)(lds + rbase + aoff[2]);
    af[3] = *(const v4i*)(lds + rbase + aoff[3]);
    if (st) ASYNC16(gA[1] + kt, lds + sbase + dA[1]);
    __builtin_amdgcn_s_barrier();
    __builtin_amdgcn_s_setprio(1);
    MFMA2(2)
    __builtin_amdgcn_s_setprio(0);
    __builtin_amdgcn_s_barrier();
    asm volatile("" ::: "memory");
    // ---- phase 2: A frags 4,5 ; stage B-chunk 0
    af[4] = *(const v4i*)(lds + rbase + aoff[4]);
    af[5] = *(const v4i*)(lds + rbase + aoff[5]);
    if (st) ASYNC16(gB[0] + kt, lds + sbase + dB[0]);
    __builtin_amdgcn_s_barrier();
    __builtin_amdgcn_s_setprio(1);
    MFMA2(4)
    __builtin_amdgcn_s_setprio(0);
    __builtin_amdgcn_s_barrier();
    asm volatile("" ::: "memory");
    // ---- phase 3: A frags 6,7 ; stage B-chunk 1 ; counted vmcnt (tile t+1 landed)
    af[6] = *(const v4i*)(lds + rbase + aoff[6]);
    af[7] = *(const v4i*)(lds + rbase + aoff[7]);
    if (st) ASYNC16(gB[1] + kt, lds + sbase + dB[1]);
    if (t < 30)      asm volatile("s_waitcnt vmcnt(4)" ::: "memory");
    else if (t == 30) asm volatile("s_waitcnt vmcnt(0)" ::: "memory");
    __builtin_amdgcn_s_barrier();
    __builtin_amdgcn_s_setprio(1);
    MFMA2(6)
    __builtin_amdgcn_s_setprio(0);
    __builtin_amdgcn_s_barrier();
    asm volatile("" ::: "memory");
    rbase = (rbase == 2 * SLOT) ? 0 : rbase + SLOT;
    sbase = (sbase == 2 * SLOT) ? 0 : sbase + SLOT;
  }
#undef MFMA2

  // double accumulators (midpoint = odd integer), then apply risky corrections
#pragma unroll
  for (int m = 0; m < 8; m++)
#pragma unroll
    for (int n = 0; n < 4; n++) acc[m][n] = acc[m][n] + acc[m][n];

  const int crow0 = brow + wr * 128;
  const int ccol0 = bcol + wc * 64;

#define CORR(J)                                                                \
  {                                                                            \
    _Pragma("unroll") for (int m = 0; m < 8; m++) {                            \
      _Pragma("unroll") for (int r = 0; r < 4; r++) {                          \
        int grow = crow0 + m * 16 + ((lane >> 4) << 2) + r;                    \
        int xv = (int)A[(size_t)grow * K_DIM + k];                             \
        acc[m][J][r] += sv * xv;                                               \
      }                                                                        \
    }                                                                          \
  }

  {
    int bkt = (bcol + wc * 64) >> 7;  // 128-col bucket containing this wave's 64 cols
    int cnt = counts[bkt];
    if (cnt > BUCKET_CAP) cnt = BUCKET_CAP;
    const int* bk = buckets + bkt * BUCKET_CAP;
    for (int e = 0; e < cnt; ++e) {
      int word = bk[e];
      int k = word & 2047;
      int nc = (word >> 11) & 8191;
      int sv = ((word >> 24) & 1) ? -1 : 1;
      if (((nc >> 6) & 1) == (wc & 1) && (nc & 15) == (lane & 15)) {
        int j = (nc >> 4) & 3;
        switch (j) {
          case 0: CORR(0); break;
          case 1: CORR(1); break;
          case 2: CORR(2); break;
          case 3: CORR(3); break;
        }
      }
    }
  }
#undef CORR

  // epilogue: C[m][n] = (2*acc_corrected) * (scale_m/2) + bias[n]  (normal cached stores)
#pragma unroll
  for (int m = 0; m < 8; m++) {
#pragma unroll
    for (int r = 0; r < 4; r++) {
      int grow = crow0 + m * 16 + ((lane >> 4) << 2) + r;
      float sc = scales[grow] * 0.5f;
      float* crow = C + (size_t)grow * N_DIM;
#pragma unroll
      for (int n = 0; n < 4; n++) {
        int gcol = ccol0 + n * 16 + (lane & 15);
        crow[gcol] = (float)acc[m][n][r] * sc + bias[gcol];
      }
    }
  }
}

extern "C" void kernel_launch(void* const* d_in, const int* in_sizes, int n_in,
                              void* d_out, int out_size, void* d_ws, size_t ws_size,
                              hipStream_t stream) {
  const float* x = (const float*)d_in[0];
  const float* w = (const float*)d_in[1];
  const float* bias = (const float*)d_in[2];
  float* out = (float*)d_out;

  char* ws = (char*)d_ws;
  float* s1 = (float*)(ws);                          // 512 KiB
  float* s2 = (float*)(ws + 0x100000);               // 16 KiB
  float* gamma_f = (float*)(ws + 0x110000);          // 4 B
  float* scales = (float*)(ws + 0x120000);           // 32 KiB
  int* counts = (int*)(ws + 0x130000);               // 64 * 4 B
  int* buckets = (int*)(ws + 0x131000);              // 256 KiB
  int8_t* Aq = (int8_t*)(ws + 0x200000);                             // 16 MiB
  int8_t* Wq = (int8_t*)(ws + 0x200000 + (size_t)M_DIM * K_DIM);     // 16 MiB

  abssum_stage1<<<512, 256, 0, stream>>>(w, s1);
  abssum_stage2<<<16, 256, 0, stream>>>(s1, s2);
  gamma_stage3<<<1, 256, 0, stream>>>(s2, gamma_f);
  zero_counts<<<1, 64, 0, stream>>>(counts);
  wq_kernel<<<(N_DIM * K_DIM / 4 + 255) / 256, 256, 0, stream>>>(
      (const float4*)w, gamma_f, (int*)Wq, counts, buckets);
  lnq_kernel<<<M_DIM, 256, 0, stream>>>(x, gamma_f, Aq, scales);
  gemm_i8_kernel<<<1024, 512, 0, stream>>>(Aq, Wq, scales, bias, counts, buckets, out);
}

// Round 14
// 274.334 us; speedup vs baseline: 1.0697x; 1.0697x over previous
//
#include <hip/hip_runtime.h>
#include <stdint.h>

typedef int v4i __attribute__((ext_vector_type(4)));

#define M_DIM 8192   // B*S = 2*4096
#define N_DIM 8192   // OUT
#define K_DIM 2048   // IN
#define RISKY_TAU 1e-4f
#define BUCKET_CAP 1024
#define SLOT 65536   // LDS buffer: A[256][128] 32KB + B[256][128] 32KB

// async global->LDS, 16B per lane (dest = wave-uniform base + lane*16)
#define ASYNC16(g, l) __builtin_amdgcn_global_load_lds(                        \
    (const __attribute__((address_space(1))) void*)(uintptr_t)(g),             \
    (__attribute__((address_space(3))) void*)(uint32_t)(uintptr_t)(l), 16, 0, 0)

// ---------------- 1) numpy-pairwise f32 sum of |w| ----------------
__global__ __launch_bounds__(256) void abssum_stage1(const float* __restrict__ w,
                                                     float* __restrict__ s1) {
  int b = blockIdx.x * 256 + threadIdx.x;  // 131072 leaf blocks of 128
  const float* p = w + (size_t)b * 128;
  float r[8];
#pragma unroll
  for (int j = 0; j < 8; j++) r[j] = fabsf(p[j]);
  for (int i = 8; i < 128; i += 8) {
#pragma unroll
    for (int j = 0; j < 8; j++) r[j] += fabsf(p[i + j]);
  }
  s1[b] = ((r[0] + r[1]) + (r[2] + r[3])) + ((r[4] + r[5]) + (r[6] + r[7]));
}

__global__ __launch_bounds__(256) void abssum_stage2(const float* __restrict__ s1,
                                                     float* __restrict__ s2) {
  int t = blockIdx.x * 256 + threadIdx.x;  // 4096 threads
  float v[32];
#pragma unroll
  for (int i = 0; i < 32; i++) v[i] = s1[t * 32 + i];
#pragma unroll
  for (int s = 1; s < 32; s *= 2) {
#pragma unroll
    for (int i = 0; i < 32; i += 2 * s) v[i] += v[i + s];
  }
  s2[t] = v[0];
}

__global__ __launch_bounds__(256) void gamma_stage3(const float* __restrict__ s2,
                                                    float* __restrict__ gp) {
  int t = threadIdx.x;  // 256 threads, one block
  float v[16];
#pragma unroll
  for (int i = 0; i < 16; i++) v[i] = s2[t * 16 + i];
#pragma unroll
  for (int s = 1; s < 16; s *= 2) {
#pragma unroll
    for (int i = 0; i < 16; i += 2 * s) v[i] += v[i + s];
  }
  __shared__ float sm[256];
  sm[t] = v[0];
  for (int s = 1; s < 256; s *= 2) {
    __syncthreads();
    if ((t & (2 * s - 1)) == 0) sm[t] += sm[t + s];
  }
  __syncthreads();
  if (t == 0) {
    float g = sm[0] * 0x1p-24f;  // /(8192*2048), exact pow2 scale
    gp[0] = fmaxf(g, 1e-5f);
  }
}

__global__ void zero_counts(int* __restrict__ counts) {
  counts[threadIdx.x] = 0;
}

// ---------------- 2) ternary weight quant + risky-midpoint detection ----------------
__global__ __launch_bounds__(256) void wq_kernel(const float4* __restrict__ w4,
                                                 const float* __restrict__ gp,
                                                 int* __restrict__ wq,
                                                 int* __restrict__ counts,
                                                 int* __restrict__ buckets) {
  int i = blockIdx.x * 256 + threadIdx.x;
  float g = gp[0];
  float4 v = w4[i];
  float e[4] = {v.x, v.y, v.z, v.w};
  int q[4];
#pragma unroll
  for (int c = 0; c < 4; c++) {
    q[c] = (int)rintf(fminf(fmaxf(e[c] / g, -1.0f), 1.0f));
    float t = fabsf(e[c]) / g;
    if (fabsf(t - 0.5f) < RISKY_TAU) {
      int flat = i * 4 + c;
      int n = flat >> 11;          // weight row (output col)
      int k = flat & 2047;
      int sgn_neg = (e[c] < 0.0f) ? 1 : 0;
      int sbit = (q[c] == 0) ? sgn_neg : (1 - sgn_neg);
      int b = n >> 7;
      int idx = atomicAdd(&counts[b], 1);
      if (idx < BUCKET_CAP)
        buckets[b * BUCKET_CAP + idx] = k | (n << 11) | (sbit << 24);
    }
  }
  wq[i] = (q[0] & 0xFF) | ((q[1] & 0xFF) << 8) | ((q[2] & 0xFF) << 16) | ((q[3] & 0xFF) << 24);
}

// ---------------- 3) fused LayerNorm + absmax int8 quant (one block per row) ----------------
__global__ __launch_bounds__(256) void lnq_kernel(const float* __restrict__ x,
                                                  const float* __restrict__ gp,
                                                  int8_t* __restrict__ xq,
                                                  float* __restrict__ scales) {
  const int row = blockIdx.x;
  const int t = threadIdx.x;
  const float4* xr = (const float4*)(x + (size_t)row * K_DIM);
  float4 a = xr[t];
  float4 b = xr[t + 256];
  double v[8] = {a.x, a.y, a.z, a.w, b.x, b.y, b.z, b.w};
  double s = 0.0, ss = 0.0;
#pragma unroll
  for (int i = 0; i < 8; i++) { s += v[i]; ss += v[i] * v[i]; }
  __shared__ double sm1[256], sm2[256];
  sm1[t] = s; sm2[t] = ss;
  __syncthreads();
  for (int off = 128; off > 0; off >>= 1) {
    if (t < off) { sm1[t] += sm1[t + off]; sm2[t] += sm2[t + off]; }
    __syncthreads();
  }
  double mu = sm1[0] * (1.0 / 2048.0);
  double var = sm2[0] * (1.0 / 2048.0) - mu * mu;  // biased variance
  double inv = 1.0 / sqrt(var + 1e-5);
  __syncthreads();
  double mx = 0.0;
#pragma unroll
  for (int i = 0; i < 8; i++) {
    v[i] = (v[i] - mu) * inv;
    double av = fabs(v[i]);
    if (av > mx) mx = av;
  }
  sm1[t] = mx;
  __syncthreads();
  for (int off = 128; off > 0; off >>= 1) {
    if (t < off) sm1[t] = fmax(sm1[t], sm1[t + off]);
    __syncthreads();
  }
  double eta = fmax(sm1[0], 1e-5);
  double r = 127.0 / eta;
  int q[8];
#pragma unroll
  for (int i = 0; i < 8; i++) {
    double qq = rint(v[i] * r);  // round-half-even, then clip
    qq = fmin(fmax(qq, -128.0), 127.0);
    q[i] = (int)qq;
  }
  int p0 = (q[0] & 0xFF) | ((q[1] & 0xFF) << 8) | ((q[2] & 0xFF) << 16) | ((q[3] & 0xFF) << 24);
  int p1 = (q[4] & 0xFF) | ((q[5] & 0xFF) << 8) | ((q[6] & 0xFF) << 16) | ((q[7] & 0xFF) << 24);
  int* orow = (int*)(xq + (size_t)row * K_DIM);
  orow[t] = p0;
  orow[t + 256] = p1;
  if (t == 0) scales[row] = (float)((double)gp[0] * eta * (1.0 / 127.0));
}

// ---------------- 4) int8 MFMA GEMM: 256x256 tile, BK=128, 2-phase double-buffer --------
// r12 locality (slab swizzle, FETCH 118MB) + r8/r9-proven sync scaled to BK=128:
// 16 K-steps, ONE __syncthreads per step; per-step MFMA (~2200cyc/CU) amortizes the
// ~3000cyc/step fixed overhead 2x vs BK=64. Staging: 8x1KB chunks/wave (8 rows x 128B),
// bijective sl^(r&7) swizzle (reads <=2-way = free); k-half fragment select = ^64.
__global__ __launch_bounds__(512, 2) void gemm_i8_kernel(const int8_t* __restrict__ A,
                                                         const int8_t* __restrict__ B,
                                                         const float* __restrict__ scales,
                                                         const float* __restrict__ bias,
                                                         const int* __restrict__ counts,
                                                         const int* __restrict__ buckets,
                                                         float* __restrict__ C) {
  __shared__ alignas(16) int8_t lds[2 * SLOT];  // 128 KiB
  const int tid = threadIdx.x;
  const int wave = tid >> 6;   // 0..7
  const int lane = tid & 63;

  // XCD slab swizzle: 1024 blocks, xcd = b&7 owns tile rows [4*xcd, 4*xcd+4), col-major
  const int b = blockIdx.x;
  const int tr = (b & 7) * 4 + ((b >> 3) & 3);
  const int tc = b >> 5;
  const int brow = tr * 256;
  const int bcol = tc * 256;

  // staging: per matrix 32 chunks of 1KB (8 rows x 128B); wave w stages chunks {4w..4w+3}.
  // lane -> row-in-chunk (lane>>3), slot (lane&7); source col = (slot ^ row&7)*16.
  const int scol = ((lane & 7) ^ (lane >> 3)) << 4;
  const int8_t* gA[4];
  const int8_t* gB[4];
  int dA[4], dB[4];
#pragma unroll
  for (int c = 0; c < 4; c++) {
    int ch = wave * 4 + c;               // chunk 0..31
    int r = ch * 8 + (lane >> 3);        // tile row staged by this lane
    gA[c] = A + (size_t)(brow + r) * K_DIM + scol;
    gB[c] = B + (size_t)(bcol + r) * K_DIM + scol;
    dA[c] = ch * 1024;                   // wave-uniform LDS base (+lane*16 by HW)
    dB[c] = 32768 + ch * 1024;
  }

  // fragment read offsets (swizzled), buffer-relative; k-half 1 = ^64
  const int wr = wave >> 2;    // 0..1  (M half)
  const int wc = wave & 3;     // 0..3  (N quarter)
  const int swz = (((lane >> 4) ^ (lane & 7)) << 4);  // slot*16, rows mod 8 = lane&7
  int aoff[8], boff[4];
#pragma unroll
  for (int m = 0; m < 8; m++)
    aoff[m] = (wr * 128 + m * 16 + (lane & 15)) * 128 + swz;
#pragma unroll
  for (int n = 0; n < 4; n++)
    boff[n] = 32768 + (wc * 64 + n * 16 + (lane & 15)) * 128 + swz;

  v4i acc[8][4];
  const v4i vzero = {0, 0, 0, 0};
#pragma unroll
  for (int m = 0; m < 8; m++)
#pragma unroll
    for (int n = 0; n < 4; n++) acc[m][n] = vzero;

  // prologue: stage tile 0 -> buf 0 (8 loads/wave); drain
#pragma unroll
  for (int c = 0; c < 4; c++) {
    ASYNC16(gA[c], lds + dA[c]);
    ASYNC16(gB[c], lds + dB[c]);
  }
  __syncthreads();  // vmcnt(0): tile 0 landed

  int cur = 0;
  for (int t = 0; t < 16; ++t) {
    // issue next-tile staging first (hides under this tile's ds_read+MFMA)
    if (t < 15) {
      const int kt = (t + 1) * 128;
      const int sb = (cur ^ 1) * SLOT;
#pragma unroll
      for (int c = 0; c < 4; c++) {
        ASYNC16(gA[c] + kt, lds + sb + dA[c]);
        ASYNC16(gB[c] + kt, lds + sb + dB[c]);
      }
    }
    const int rb = cur * SLOT;
#pragma unroll
    for (int kh = 0; kh < 2; kh++) {
      const int kx = kh << 6;  // ^64 selects K-half 1
      v4i bf[4], af[8];
#pragma unroll
      for (int n = 0; n < 4; n++) bf[n] = *(const v4i*)(lds + rb + (boff[n] ^ kx));
#pragma unroll
      for (int m = 0; m < 8; m++) af[m] = *(const v4i*)(lds + rb + (aoff[m] ^ kx));
      __builtin_amdgcn_s_setprio(1);
#pragma unroll
      for (int m = 0; m < 8; m++)
#pragma unroll
        for (int n = 0; n < 4; n++)
          acc[m][n] = __builtin_amdgcn_mfma_i32_16x16x64_i8(af[m], bf[n], acc[m][n], 0, 0, 0);
      __builtin_amdgcn_s_setprio(0);
    }
    __syncthreads();  // one drain per K-step: tile t+1 landed; ds_reads of buf done
    cur ^= 1;
  }

  // double accumulators (midpoint = odd integer), then apply risky corrections
#pragma unroll
  for (int m = 0; m < 8; m++)
#pragma unroll
    for (int n = 0; n < 4; n++) acc[m][n] = acc[m][n] + acc[m][n];

  const int crow0 = brow + wr * 128;
  const int ccol0 = bcol + wc * 64;

#define CORR(J)                                                                \
  {                                                                            \
    _Pragma("unroll") for (int m = 0; m < 8; m++) {                            \
      _Pragma("unroll") for (int r = 0; r < 4; r++) {                          \
        int grow = crow0 + m * 16 + ((lane >> 4) << 2) + r;                    \
        int xv = (int)A[(size_t)grow * K_DIM + k];                             \
        acc[m][J][r] += sv * xv;                                               \
      }                                                                        \
    }                                                                          \
  }

  {
    int bkt = (bcol + wc * 64) >> 7;  // 128-col bucket containing this wave's 64 cols
    int cnt = counts[bkt];
    if (cnt > BUCKET_CAP) cnt = BUCKET_CAP;
    const int* bk = buckets + bkt * BUCKET_CAP;
    for (int e = 0; e < cnt; ++e) {
      int word = bk[e];
      int k = word & 2047;
      int nc = (word >> 11) & 8191;
      int sv = ((word >> 24) & 1) ? -1 : 1;
      if (((nc >> 6) & 1) == (wc & 1) && (nc & 15) == (lane & 15)) {
        int j = (nc >> 4) & 3;
        switch (j) {
          case 0: CORR(0); break;
          case 1: CORR(1); break;
          case 2: CORR(2); break;
          case 3: CORR(3); break;
        }
      }
    }
  }
#undef CORR

  // epilogue: C[m][n] = (2*acc_corrected) * (scale_m/2) + bias[n]  (normal cached stores)
#pragma unroll
  for (int m = 0; m < 8; m++) {
#pragma unroll
    for (int r = 0; r < 4; r++) {
      int grow = crow0 + m * 16 + ((lane >> 4) << 2) + r;
      float sc = scales[grow] * 0.5f;
      float* crow = C + (size_t)grow * N_DIM;
#pragma unroll
      for (int n = 0; n < 4; n++) {
        int gcol = ccol0 + n * 16 + (lane & 15);
        crow[gcol] = (float)acc[m][n][r] * sc + bias[gcol];
      }
    }
  }
}

extern "C" void kernel_launch(void* const* d_in, const int* in_sizes, int n_in,
                              void* d_out, int out_size, void* d_ws, size_t ws_size,
                              hipStream_t stream) {
  const float* x = (const float*)d_in[0];
  const float* w = (const float*)d_in[1];
  const float* bias = (const float*)d_in[2];
  float* out = (float*)d_out;

  char* ws = (char*)d_ws;
  float* s1 = (float*)(ws);                          // 512 KiB
  float* s2 = (float*)(ws + 0x100000);               // 16 KiB
  float* gamma_f = (float*)(ws + 0x110000);          // 4 B
  float* scales = (float*)(ws + 0x120000);           // 32 KiB
  int* counts = (int*)(ws + 0x130000);               // 64 * 4 B
  int* buckets = (int*)(ws + 0x131000);              // 256 KiB
  int8_t* Aq = (int8_t*)(ws + 0x200000);                             // 16 MiB
  int8_t* Wq = (int8_t*)(ws + 0x200000 + (size_t)M_DIM * K_DIM);     // 16 MiB

  abssum_stage1<<<512, 256, 0, stream>>>(w, s1);
  abssum_stage2<<<16, 256, 0, stream>>>(s1, s2);
  gamma_stage3<<<1, 256, 0, stream>>>(s2, gamma_f);
  zero_counts<<<1, 64, 0, stream>>>(counts);
  wq_kernel<<<(N_DIM * K_DIM / 4 + 255) / 256, 256, 0, stream>>>(
      (const float4*)w, gamma_f, (int*)Wq, counts, buckets);
  lnq_kernel<<<M_DIM, 256, 0, stream>>>(x, gamma_f, Aq, scales);
  gemm_i8_kernel<<<1024, 512, 0, stream>>>(Aq, Wq, scales, bias, counts, buckets, out);
}